// Round 10
// baseline (389.158 us; speedup 1.0000x reference)
//
#include <hip/hip_runtime.h>
#include <hip/hip_bf16.h>

typedef unsigned short u16;
typedef unsigned int u32;
typedef __attribute__((ext_vector_type(8))) short bf16x8;
typedef __attribute__((ext_vector_type(4))) float f32x4;
typedef __attribute__((ext_vector_type(16))) float f32x16;

#define T_TOK 8192
#define DIN 4096
#define DOUT 4096
#define N_SEQS 4
#define N_ADPT 8
#define MAXR 64
#define CACHE_LEN 512

__device__ __forceinline__ u16 f2bf(float f) {
    u32 u = __builtin_bit_cast(u32, f);
    u += 0x7fffu + ((u >> 16) & 1u);   // RNE
    return (u16)(u >> 16);
}

__device__ __forceinline__ void load_lds16(const u16* g, u16* l) {
    __builtin_amdgcn_global_load_lds(
        (const __attribute__((address_space(1))) u32*)g,
        (__attribute__((address_space(3))) u32*)l, 16, 0, 0);
}

// ---------------- fp32 -> bf16 convert (vectorized) ----------------
__global__ void cvt_kernel(const float* __restrict__ in, u16* __restrict__ out, int n4) {
    int i = blockIdx.x * blockDim.x + threadIdx.x;
    int stride = gridDim.x * blockDim.x;
    for (; i < n4; i += stride) {
        float4 v = reinterpret_cast<const float4*>(in)[i];
        ushort4 o;
        o.x = f2bf(v.x); o.y = f2bf(v.y); o.z = f2bf(v.z); o.w = f2bf(v.w);
        reinterpret_cast<ushort4*>(out)[i] = o;
    }
}

// ------------- build Bt[a][n][r] bf16 from b_cache via page table -------------
__global__ void build_bt(const float* __restrict__ b_cache, const int* __restrict__ rpt,
                         u16* __restrict__ Bt) {
    int id = blockIdx.x * 256 + threadIdx.x;      // total 8*8*4096 = 262144
    int n  = id & (DOUT - 1);
    int rb = (id >> 12) & 7;
    int a  = id >> 15;
    union { u16 u[8]; uint4 v; } pack;
    #pragma unroll
    for (int j = 0; j < 8; ++j) {
        int r = rb * 8 + j;
        int page = rpt[a * MAXR + r];
        pack.u[j] = f2bf(b_cache[(long)page * DOUT + n]);
    }
    *reinterpret_cast<uint4*>(&Bt[((long)(a * DOUT + n)) * MAXR + rb * 8]) = pack.v;
}

// ------------- xa[t][r] = scale * (x[t] . A[page(adapter,r)]), masked -------------
// R10: double-buffered staging + counted vmcnt(3) (R4-proven pattern) -> latency hidden.
__launch_bounds__(256)
__global__ void xa_kernel(const u16* __restrict__ xb, const u16* __restrict__ ab,
                          const int* __restrict__ b_start_loc,
                          const int* __restrict__ b_adapter_ids,
                          const float* __restrict__ b_scaling,
                          const int* __restrict__ rpt,
                          const int* __restrict__ ranks,
                          u16* __restrict__ xa) {
    int t0 = blockIdx.x * 128;
    int seg = 0;
    #pragma unroll
    for (int i = 1; i < N_SEQS; ++i) if (b_start_loc[i] <= t0) seg = i;
    int adapter = b_adapter_ids[seg];
    float scale = b_scaling[seg];
    int rank = ranks[adapter];

    __shared__ __attribute__((aligned(16))) u16 As[2 * 4096];   // 2 x (128x32)
    __shared__ __attribute__((aligned(16))) u16 Bs[2 * 2048];   // 2 x (64x32)

    int tid = threadIdx.x;
    int lane = tid & 63, wave = tid >> 6;
    int lr = lane & 15, lk = lane >> 4;

    int e0 = wave * 64 + lane;               // [0,256)
    int e1 = 256 + e0;                       // [256,512)
    int ra0 = e0 >> 2, ca0 = (e0 & 3) * 8;
    int ra1 = e1 >> 2, ca1 = (e1 & 3) * 8;
    const u16* gA0 = xb + (long)(t0 + ra0) * DIN + ca0;
    const u16* gA1 = xb + (long)(t0 + ra1) * DIN + ca1;
    int rB = ra0;
    int page = rpt[adapter * MAXR + rB];
    const u16* gB = ab + (long)page * DIN + ca0;

    f32x4 acc[2][4] = {};

    #define XSTAGE(s, buf)                                                         \
        do {                                                                       \
            load_lds16(gA0 + (s) * 32, As + (buf) * 4096 + wave * 512);            \
            load_lds16(gA1 + (s) * 32, As + (buf) * 4096 + 2048 + wave * 512);     \
            load_lds16(gB + (s) * 32,  Bs + (buf) * 2048 + wave * 512);            \
        } while (0)

    XSTAGE(0, 0);
    for (int s = 0; s < 128; ++s) {
        int b = s & 1;
        if (s < 127) {
            XSTAGE(s + 1, b ^ 1);
            asm volatile("s_waitcnt vmcnt(3)" ::: "memory");   // step s landed; s+1 in flight
        } else {
            asm volatile("s_waitcnt vmcnt(0)" ::: "memory");
        }
        __builtin_amdgcn_s_barrier();
        __builtin_amdgcn_sched_barrier(0);

        bf16x8 af[2], bfr[4];
        #pragma unroll
        for (int m = 0; m < 2; ++m)
            af[m] = *(const bf16x8*)&As[b * 4096 + (wave * 32 + m * 16 + lr) * 32 + lk * 8];
        #pragma unroll
        for (int n = 0; n < 4; ++n)
            bfr[n] = *(const bf16x8*)&Bs[b * 2048 + (n * 16 + lr) * 32 + lk * 8];
        #pragma unroll
        for (int m = 0; m < 2; ++m)
            #pragma unroll
            for (int n = 0; n < 4; ++n)
                acc[m][n] = __builtin_amdgcn_mfma_f32_16x16x32_bf16(af[m], bfr[n], acc[m][n], 0, 0, 0);

        __builtin_amdgcn_s_barrier();          // reads done before next overwrite
        __builtin_amdgcn_sched_barrier(0);
    }
    #undef XSTAGE

    #pragma unroll
    for (int m = 0; m < 2; ++m) {
        int trow = t0 + wave * 32 + m * 16 + lk * 4;
        #pragma unroll
        for (int n = 0; n < 4; ++n) {
            int r = n * 16 + lr;
            #pragma unroll
            for (int j = 0; j < 4; ++j) {
                float v = (r < rank) ? acc[m][n][j] * scale : 0.0f;
                xa[(long)(trow + j) * MAXR + r] = f2bf(v);
            }
        }
    }
}

// ------------- main GEMM: 256x256, BK=32, reg-pipelined, 32x32x16 MFMA -------------
// R10 change: mfma_f32_32x32x16_bf16 (matrix-pipe -17% per m119 2495-vs-2176 TF; half
// the MFMA instruction count). Operand bytes unchanged (12 ds_read_b128/wave/tile).
// Fragment addressing: row = base + (lane&31), k = (lane>>5)*8 + j, ks in {0,1};
// C/D: col = lane&31, row = (reg&3) + 8*(reg>>2) + 4*(lane>>5)  [m74/m101-verified].
__launch_bounds__(512, 2)
__global__ void gemm256_kernel(const u16* __restrict__ xb, const u16* __restrict__ wb,
                               const float* __restrict__ bias,
                               const u16* __restrict__ xa, const u16* __restrict__ Bt,
                               const int* __restrict__ b_start_loc,
                               const int* __restrict__ b_adapter_ids,
                               float* __restrict__ out) {
    __shared__ __attribute__((aligned(16))) u16 lds[32768];   // 64 KiB: 2 buf x (A 16KB + B 16KB)

    // T1: XCD-aware swizzle (nwg=512 % 8 == 0 -> bijective)
    int bid = blockIdx.x;
    int wgid = (bid & 7) * 64 + (bid >> 3);
    int mt = wgid >> 4, nt = wgid & 15;
    int brow = mt * 256, bcol = nt * 256;

    int seg = 0;
    #pragma unroll
    for (int i = 1; i < N_SEQS; ++i) if (b_start_loc[i] <= brow) seg = i;
    int adapter = b_adapter_ids[seg];

    int tid = threadIdx.x;
    int lane = tid & 63, wave = tid >> 6;
    int wm = wave >> 2, wn = wave & 3;       // 2x4 wave grid, per-wave C = 128x64
    int l5 = lane & 31, k8 = lane >> 5;
    int lr = lane & 15, lk = lane >> 4;      // (used by staging geometry only)
    (void)lr; (void)lk;

    // ---- staging geometry (linear LDS dest, pre-swizzled source; R6/R8-verified) ----
    int lsw = (tid & 7) ^ ((tid >> 3) & 7);
    int c8  = (lsw & 3) * 8;
    int r0  = (tid >> 3) * 2 + (lsw >> 2);            // q=0 global row; q=1 adds 128
    const long odA0 = (long)(brow + r0) * DIN + c8;           // xb, q=0
    const long odA1 = odA0 + 128L * DIN;                      // xb, q=1
    const long odB0 = (long)(bcol + r0) * DIN + c8;           // wb
    const long odB1 = odB0 + 128L * DIN;
    const long o6A0 = (long)(brow + r0) * MAXR + c8;          // xa (LoRA)
    const long o6A1 = o6A0 + 128L * MAXR;
    const long o6B0 = (long)(adapter * DOUT + bcol + r0) * MAXR + c8;  // Bt
    const long o6B1 = o6B0 + 128L * MAXR;

    #define STAGE(T, buf)                                                          \
        do {                                                                       \
            u16* dA = lds + (buf) * 8192 + tid * 8;                                \
            u16* dB = lds + 16384 + (buf) * 8192 + tid * 8;                        \
            if ((T) < 128) {                                                       \
                long ko = (long)(T) * 32;                                          \
                load_lds16(xb + odA0 + ko, dA);                                    \
                load_lds16(xb + odA1 + ko, dA + 4096);                             \
                load_lds16(wb + odB0 + ko, dB);                                    \
                load_lds16(wb + odB1 + ko, dB + 4096);                             \
            } else {                                                               \
                long ko = (long)((T) - 128) * 32;                                  \
                load_lds16(xa + o6A0 + ko, dA);                                    \
                load_lds16(xa + o6A1 + ko, dA + 4096);                             \
                load_lds16(Bt + o6B0 + ko, dB);                                    \
                load_lds16(Bt + o6B1 + ko, dB + 4096);                             \
            }                                                                      \
        } while (0)

    // ---- 32x32 fragment byte offsets inside a [128-storage-row x 128 B] tile ----
    // frag row r = R + l5 (R mult of 32): srr = r>>1 -> (srr&7) = (l5>>1)&7;
    // logical slot = (r&1)*4 + ks*2 + k8 ; physical = logical ^ (srr&7).
    const int lb0 = (l5 >> 1) * 128 + (((((l5 & 1) << 2) + 0 + k8) ^ ((l5 >> 1) & 7)) * 16); // ks=0
    const int lb1 = (l5 >> 1) * 128 + (((((l5 & 1) << 2) + 2 + k8) ^ ((l5 >> 1) & 7)) * 16); // ks=1
    const char* ldsc = (const char*)lds;
    const int cA0 = wm * 8192 + lb0, cA1 = wm * 8192 + lb1;            // + buf*16384 bytes
    const int cB0 = 32768 + wn * 4096 + lb0, cB1 = 32768 + wn * 4096 + lb1;

    // FA[8]: idx = ks*4 + mi ; FB[4]: idx = ks*2 + ni
    #define READF(FA, FB, par)                                                     \
        do {                                                                       \
            const char* pA0 = ldsc + (par) * 16384 + cA0;                          \
            const char* pA1 = ldsc + (par) * 16384 + cA1;                          \
            const char* pB0 = ldsc + (par) * 16384 + cB0;                          \
            const char* pB1 = ldsc + (par) * 16384 + cB1;                          \
            FB[0] = *(const bf16x8*)(pB0);        FB[1] = *(const bf16x8*)(pB0 + 2048); \
            FB[2] = *(const bf16x8*)(pB1);        FB[3] = *(const bf16x8*)(pB1 + 2048); \
            _Pragma("unroll")                                                      \
            for (int mi = 0; mi < 4; ++mi) {                                       \
                FA[mi]     = *(const bf16x8*)(pA0 + mi * 2048);                    \
                FA[4 + mi] = *(const bf16x8*)(pA1 + mi * 2048);                    \
            }                                                                      \
        } while (0)

    #define MFMA16(FA, FB)                                                         \
        do {                                                                       \
            __builtin_amdgcn_s_setprio(1);                                         \
            _Pragma("unroll")                                                      \
            for (int ks = 0; ks < 2; ++ks)                                         \
                _Pragma("unroll")                                                  \
                for (int mi = 0; mi < 4; ++mi)                                     \
                    _Pragma("unroll")                                              \
                    for (int ni = 0; ni < 2; ++ni)                                 \
                        acc[mi][ni] = __builtin_amdgcn_mfma_f32_32x32x16_bf16(     \
                            FA[ks * 4 + mi], FB[ks * 2 + ni], acc[mi][ni], 0, 0, 0); \
            __builtin_amdgcn_s_setprio(0);                                         \
        } while (0)

    #define ENDBAR()                                                               \
        do {                                                                       \
            asm volatile("s_waitcnt lgkmcnt(0)" ::: "memory");                     \
            __builtin_amdgcn_sched_barrier(0);                                     \
            __builtin_amdgcn_s_barrier();                                          \
        } while (0)

    f32x16 acc[4][2] = {};
    bf16x8 fA0[8], fB0[4], fA1[8], fB1[4];

    // ---- prologue: stage tiles 0,1; preload tile-0 fragments ----
    STAGE(0, 0);
    STAGE(1, 1);
    asm volatile("s_waitcnt vmcnt(4)" ::: "memory");   // tile0 landed; tile1 in flight
    __builtin_amdgcn_s_barrier();
    READF(fA0, fB0, 0);
    ENDBAR();

    for (int t = 0; t < 130; t += 2) {
        // ---- even half: consume set0 (tile t), preload set1 (tile t+1) ----
        STAGE((t + 2 < 130) ? t + 2 : 129, t & 1);
        asm volatile("s_waitcnt vmcnt(4)" ::: "memory"); // tile t+1 landed; t+2 in flight
        __builtin_amdgcn_s_barrier();                    // t+1 visible
        READF(fA1, fB1, (t + 1) & 1);                    // independent of MFMA below
        MFMA16(fA0, fB0);
        ENDBAR();                                        // reads drained before next DMA

        // ---- odd half: consume set1 (tile t+1), preload set0 (tile t+2) ----
        STAGE((t + 3 < 130) ? t + 3 : 129, (t + 1) & 1);
        asm volatile("s_waitcnt vmcnt(4)" ::: "memory");
        __builtin_amdgcn_s_barrier();
        if (t + 2 < 130) READF(fA0, fB0, t & 1);
        MFMA16(fA1, fB1);
        ENDBAR();
    }
    asm volatile("s_waitcnt vmcnt(0)" ::: "memory");   // drain ghost DMAs

    #undef STAGE
    #undef READF
    #undef MFMA16
    #undef ENDBAR

    // ---- epilogue: + bias, fp32 store (32x32 C/D layout) ----
    #pragma unroll
    for (int mi = 0; mi < 4; ++mi) {
        #pragma unroll
        for (int ni = 0; ni < 2; ++ni) {
            int ocol = bcol + wn * 64 + ni * 32 + l5;
            float bv = bias[ocol];
            #pragma unroll
            for (int g = 0; g < 4; ++g) {
                int orow = brow + wm * 128 + mi * 32 + g * 8 + k8 * 4;
                #pragma unroll
                for (int j = 0; j < 4; ++j)
                    out[(long)(orow + j) * DOUT + ocol] = acc[mi][ni][g * 4 + j] + bv;
            }
        }
    }
}

extern "C" void kernel_launch(void* const* d_in, const int* in_sizes, int n_in,
                              void* d_out, int out_size, void* d_ws, size_t ws_size,
                              hipStream_t stream) {
    const float* x          = (const float*)d_in[0];
    const float* weight     = (const float*)d_in[1];
    const float* bias       = (const float*)d_in[2];
    const float* a_cache    = (const float*)d_in[3];
    const float* b_cache    = (const float*)d_in[4];
    const int*   b_start    = (const int*)d_in[5];
    const int*   b_adapter  = (const int*)d_in[6];
    const float* b_scaling  = (const float*)d_in[7];
    const int*   rpt        = (const int*)d_in[8];
    const int*   ranks      = (const int*)d_in[9];
    float* out = (float*)d_out;

    char* ws = (char*)d_ws;
    u16* xb = (u16*)ws; ws += (size_t)T_TOK * DIN * 2;          // 64 MiB
    u16* wb = (u16*)ws; ws += (size_t)DOUT * DIN * 2;           // 32 MiB
    u16* ab = (u16*)ws; ws += (size_t)CACHE_LEN * DIN * 2;      // 4 MiB
    u16* Bt = (u16*)ws; ws += (size_t)N_ADPT * DOUT * MAXR * 2; // 4 MiB
    u16* xa = (u16*)ws; ws += (size_t)T_TOK * MAXR * 2;         // 1 MiB

    cvt_kernel<<<2048, 256, 0, stream>>>(x, xb, T_TOK * DIN / 4);
    cvt_kernel<<<2048, 256, 0, stream>>>(weight, wb, DOUT * DIN / 4);
    cvt_kernel<<<512, 256, 0, stream>>>(a_cache, ab, CACHE_LEN * DIN / 4);
    build_bt<<<(N_ADPT * 8 * DOUT) / 256, 256, 0, stream>>>(b_cache, rpt, Bt);
    xa_kernel<<<T_TOK / 128, 256, 0, stream>>>(xb, ab, b_start, b_adapter, b_scaling, rpt, ranks, xa);
    gemm256_kernel<<<(T_TOK / 256) * (DOUT / 256), 512, 0, stream>>>(xb, wb, bias, xa, Bt, b_start, b_adapter, out);
}

// Round 11
// 328.136 us; speedup vs baseline: 1.1860x; 1.1860x over previous
//
#include <hip/hip_runtime.h>
#include <hip/hip_bf16.h>

typedef unsigned short u16;
typedef unsigned int u32;
typedef __attribute__((ext_vector_type(8))) short bf16x8;
typedef __attribute__((ext_vector_type(4))) float f32x4;

#define T_TOK 8192
#define DIN 4096
#define DOUT 4096
#define N_SEQS 4
#define N_ADPT 8
#define MAXR 64
#define CACHE_LEN 512

__device__ __forceinline__ u16 f2bf(float f) {
    u32 u = __builtin_bit_cast(u32, f);
    u += 0x7fffu + ((u >> 16) & 1u);   // RNE
    return (u16)(u >> 16);
}

__device__ __forceinline__ void load_lds16(const u16* g, u16* l) {
    __builtin_amdgcn_global_load_lds(
        (const __attribute__((address_space(1))) u32*)g,
        (__attribute__((address_space(3))) u32*)l, 16, 0, 0);
}

// ---------------- fused fp32 -> bf16 convert of x, W, a_cache ----------------
__global__ void cvt_all(const float* __restrict__ x, const float* __restrict__ w,
                        const float* __restrict__ a,
                        u16* __restrict__ xb, u16* __restrict__ wb, u16* __restrict__ ab) {
    const int n_x = T_TOK * DIN / 4, n_w = DOUT * DIN / 4, n_a = CACHE_LEN * DIN / 4;
    int i = blockIdx.x * 256 + threadIdx.x;
    int stride = gridDim.x * 256;
    for (int j = i; j < n_x + n_w + n_a; j += stride) {
        const float* src; u16* dst; int k;
        if (j < n_x)            { src = x; dst = xb; k = j; }
        else if (j < n_x + n_w) { src = w; dst = wb; k = j - n_x; }
        else                    { src = a; dst = ab; k = j - n_x - n_w; }
        float4 v = reinterpret_cast<const float4*>(src)[k];
        ushort4 o;
        o.x = f2bf(v.x); o.y = f2bf(v.y); o.z = f2bf(v.z); o.w = f2bf(v.w);
        reinterpret_cast<ushort4*>(dst)[k] = o;
    }
}

// ------------- build Bt[a][n][r] bf16 from b_cache via page table -------------
__global__ void build_bt(const float* __restrict__ b_cache, const int* __restrict__ rpt,
                         u16* __restrict__ Bt) {
    int id = blockIdx.x * 256 + threadIdx.x;      // total 8*8*4096 = 262144
    int n  = id & (DOUT - 1);
    int rb = (id >> 12) & 7;
    int a  = id >> 15;
    union { u16 u[8]; uint4 v; } pack;
    #pragma unroll
    for (int j = 0; j < 8; ++j) {
        int r = rb * 8 + j;
        int page = rpt[a * MAXR + r];
        pack.u[j] = f2bf(b_cache[(long)page * DOUT + n]);
    }
    *reinterpret_cast<uint4*>(&Bt[((long)(a * DOUT + n)) * MAXR + rb * 8]) = pack.v;
}

// ------------- xa partials: K-split x4 -> xa_part[kseg][T][64] f32 -------------
// 256 blocks (token-block x K-segment): full-GPU parallelism for this
// latency-bound skinny GEMM. No atomics; xa_fin reduces.
__launch_bounds__(256)
__global__ void xa_kernel(const u16* __restrict__ xb, const u16* __restrict__ ab,
                          const int* __restrict__ b_start_loc,
                          const int* __restrict__ b_adapter_ids,
                          const int* __restrict__ rpt,
                          float* __restrict__ xa_part) {
    int tblk = blockIdx.x >> 2, kseg = blockIdx.x & 3;
    int t0 = tblk * 128;
    int seg = 0;
    #pragma unroll
    for (int i = 1; i < N_SEQS; ++i) if (b_start_loc[i] <= t0) seg = i;
    int adapter = b_adapter_ids[seg];

    __shared__ __attribute__((aligned(16))) u16 As[2 * 4096];   // 2 x (128x32)
    __shared__ __attribute__((aligned(16))) u16 Bs[2 * 2048];   // 2 x (64x32)

    int tid = threadIdx.x;
    int lane = tid & 63, wave = tid >> 6;
    int lr = lane & 15, lk = lane >> 4;

    int e0 = wave * 64 + lane;               // [0,256)
    int e1 = 256 + e0;                       // [256,512)
    int ra0 = e0 >> 2, ca0 = (e0 & 3) * 8;
    int ra1 = e1 >> 2, ca1 = (e1 & 3) * 8;
    const u16* gA0 = xb + (long)(t0 + ra0) * DIN + kseg * 1024 + ca0;
    const u16* gA1 = xb + (long)(t0 + ra1) * DIN + kseg * 1024 + ca1;
    int page = rpt[adapter * MAXR + ra0];
    const u16* gB = ab + (long)page * DIN + kseg * 1024 + ca0;

    f32x4 acc[2][4] = {};

    #define XSTAGE(s, buf)                                                         \
        do {                                                                       \
            load_lds16(gA0 + (s) * 32, As + (buf) * 4096 + wave * 512);            \
            load_lds16(gA1 + (s) * 32, As + (buf) * 4096 + 2048 + wave * 512);     \
            load_lds16(gB + (s) * 32,  Bs + (buf) * 2048 + wave * 512);            \
        } while (0)

    XSTAGE(0, 0);
    for (int s = 0; s < 32; ++s) {
        int b = s & 1;
        if (s < 31) {
            XSTAGE(s + 1, b ^ 1);
            asm volatile("s_waitcnt vmcnt(3)" ::: "memory");   // step s landed; s+1 in flight
        } else {
            asm volatile("s_waitcnt vmcnt(0)" ::: "memory");
        }
        __builtin_amdgcn_s_barrier();
        __builtin_amdgcn_sched_barrier(0);

        bf16x8 af[2], bfr[4];
        #pragma unroll
        for (int m = 0; m < 2; ++m)
            af[m] = *(const bf16x8*)&As[b * 4096 + (wave * 32 + m * 16 + lr) * 32 + lk * 8];
        #pragma unroll
        for (int n = 0; n < 4; ++n)
            bfr[n] = *(const bf16x8*)&Bs[b * 2048 + (n * 16 + lr) * 32 + lk * 8];
        #pragma unroll
        for (int m = 0; m < 2; ++m)
            #pragma unroll
            for (int n = 0; n < 4; ++n)
                acc[m][n] = __builtin_amdgcn_mfma_f32_16x16x32_bf16(af[m], bfr[n], acc[m][n], 0, 0, 0);

        __builtin_amdgcn_s_barrier();          // reads done before next overwrite
        __builtin_amdgcn_sched_barrier(0);
    }
    #undef XSTAGE

    float* dst = xa_part + (long)kseg * T_TOK * MAXR;
    #pragma unroll
    for (int m = 0; m < 2; ++m) {
        int trow = t0 + wave * 32 + m * 16 + lk * 4;
        #pragma unroll
        for (int n = 0; n < 4; ++n) {
            int r = n * 16 + lr;
            #pragma unroll
            for (int j = 0; j < 4; ++j)
                dst[(long)(trow + j) * MAXR + r] = acc[m][n][j];
        }
    }
}

// ------------- xa finalize: sum 4 partials, mask, scale, cvt -> bf16 -------------
__global__ void xa_fin(const float* __restrict__ xa_part,
                       const int* __restrict__ b_start_loc,
                       const int* __restrict__ b_adapter_ids,
                       const float* __restrict__ b_scaling,
                       const int* __restrict__ ranks,
                       u16* __restrict__ xa) {
    const int N = T_TOK * MAXR;               // 524288
    int i = blockIdx.x * 256 + threadIdx.x;
    if (i >= N) return;
    int t = i >> 6, r = i & 63;
    int seg = 0;
    #pragma unroll
    for (int s = 1; s < N_SEQS; ++s) if (b_start_loc[s] <= t) seg = s;
    int adapter = b_adapter_ids[seg];
    float v = xa_part[i] + xa_part[N + i] + xa_part[2 * N + i] + xa_part[3 * N + i];
    v = (r < ranks[adapter]) ? v * b_scaling[seg] : 0.0f;
    xa[i] = f2bf(v);
}

// ------------- main GEMM: 256x256, BK=32, register-pipelined (R9 exact) -------------
// MFMA(tile t) consumes fragments PRELOADED during interval t-1; this interval's
// ds_reads fill the other named register set with tile t+1's fragments.
__launch_bounds__(512, 2)
__global__ void gemm256_kernel(const u16* __restrict__ xb, const u16* __restrict__ wb,
                               const float* __restrict__ bias,
                               const u16* __restrict__ xa, const u16* __restrict__ Bt,
                               const int* __restrict__ b_start_loc,
                               const int* __restrict__ b_adapter_ids,
                               float* __restrict__ out) {
    __shared__ __attribute__((aligned(16))) u16 lds[32768];   // 64 KiB: 2 buf x (A 8K + B 8K u16)

    // T1: XCD-aware swizzle (nwg=512 % 8 == 0 -> bijective)
    int bid = blockIdx.x;
    int wgid = (bid & 7) * 64 + (bid >> 3);
    int mt = wgid >> 4, nt = wgid & 15;
    int brow = mt * 256, bcol = nt * 256;

    int seg = 0;
    #pragma unroll
    for (int i = 1; i < N_SEQS; ++i) if (b_start_loc[i] <= brow) seg = i;
    int adapter = b_adapter_ids[seg];

    int tid = threadIdx.x;
    int lane = tid & 63, wave = tid >> 6;
    int wm = wave >> 2, wn = wave & 3;       // 2x4 wave grid, per-wave C = 128x64
    int lr = lane & 15, lk = lane >> 4;

    // ---- staging geometry (linear LDS dest, pre-swizzled source; R6/R8-verified) ----
    int lsw = (tid & 7) ^ ((tid >> 3) & 7);
    int c8  = (lsw & 3) * 8;
    int r0  = (tid >> 3) * 2 + (lsw >> 2);            // q=0 global row; q=1 adds 128
    const long odA0 = (long)(brow + r0) * DIN + c8;           // xb, q=0
    const long odA1 = odA0 + 128L * DIN;                      // xb, q=1
    const long odB0 = (long)(bcol + r0) * DIN + c8;           // wb
    const long odB1 = odB0 + 128L * DIN;
    const long o6A0 = (long)(brow + r0) * MAXR + c8;          // xa (LoRA)
    const long o6A1 = o6A0 + 128L * MAXR;
    const long o6B0 = (long)(adapter * DOUT + bcol + r0) * MAXR + c8;  // Bt
    const long o6B1 = o6B0 + 128L * MAXR;

    #define STAGE(T, buf)                                                          \
        do {                                                                       \
            u16* dA = lds + (buf) * 8192 + tid * 8;                                \
            u16* dB = lds + 16384 + (buf) * 8192 + tid * 8;                        \
            if ((T) < 128) {                                                       \
                long ko = (long)(T) * 32;                                          \
                load_lds16(xb + odA0 + ko, dA);                                    \
                load_lds16(xb + odA1 + ko, dA + 4096);                             \
                load_lds16(wb + odB0 + ko, dB);                                    \
                load_lds16(wb + odB1 + ko, dB + 4096);                             \
            } else {                                                               \
                long ko = (long)((T) - 128) * 32;                                  \
                load_lds16(xa + o6A0 + ko, dA);                                    \
                load_lds16(xa + o6A1 + ko, dA + 4096);                             \
                load_lds16(Bt + o6B0 + ko, dB);                                    \
                load_lds16(Bt + o6B1 + ko, dB + 4096);                             \
            }                                                                      \
        } while (0)

    // lane-invariant byte offset inside a [64-storage-row x 128 B] tile (R6-verified)
    const int laneByte = (lr >> 1) * 128 + 16 * ((((lr & 1) << 2) + lk) ^ (lr >> 1));
    const char* ldsc = (const char*)lds;
    const int cA = wm * 8192 + laneByte;              // + buf*16384 bytes
    const int cB = 32768 + wn * 4096 + laneByte;      // + buf*16384 bytes

    #define READF(FA, FB, par)                                                     \
        do {                                                                       \
            const char* pA = ldsc + (par) * 16384 + cA;                            \
            const char* pB = ldsc + (par) * 16384 + cB;                            \
            _Pragma("unroll")                                                      \
            for (int ni = 0; ni < 4; ++ni) FB[ni] = *(const bf16x8*)(pB + ni * 1024); \
            _Pragma("unroll")                                                      \
            for (int mi = 0; mi < 8; ++mi) FA[mi] = *(const bf16x8*)(pA + mi * 1024); \
        } while (0)

    #define MFMA32(FA, FB)                                                         \
        do {                                                                       \
            __builtin_amdgcn_s_setprio(1);                                         \
            _Pragma("unroll")                                                      \
            for (int mi = 0; mi < 8; ++mi)                                         \
                _Pragma("unroll")                                                  \
                for (int ni = 0; ni < 4; ++ni)                                     \
                    acc[mi][ni] = __builtin_amdgcn_mfma_f32_16x16x32_bf16(         \
                        FA[mi], FB[ni], acc[mi][ni], 0, 0, 0);                     \
            __builtin_amdgcn_s_setprio(0);                                         \
        } while (0)

    #define ENDBAR()                                                               \
        do {                                                                       \
            asm volatile("s_waitcnt lgkmcnt(0)" ::: "memory");                     \
            __builtin_amdgcn_sched_barrier(0);                                     \
            __builtin_amdgcn_s_barrier();                                          \
        } while (0)

    f32x4 acc[8][4] = {};
    bf16x8 fA0[8], fB0[4], fA1[8], fB1[4];

    // ---- prologue: stage tiles 0,1; preload tile-0 fragments ----
    STAGE(0, 0);
    STAGE(1, 1);
    asm volatile("s_waitcnt vmcnt(4)" ::: "memory");   // tile0 landed; tile1 in flight
    __builtin_amdgcn_s_barrier();
    READF(fA0, fB0, 0);
    ENDBAR();

    for (int t = 0; t < 130; t += 2) {
        // ---- even half: consume set0 (tile t), preload set1 (tile t+1) ----
        STAGE((t + 2 < 130) ? t + 2 : 129, t & 1);     // buf[t&1]: tile t's frags already in regs
        asm volatile("s_waitcnt vmcnt(4)" ::: "memory"); // tile t+1 landed; t+2 in flight
        __builtin_amdgcn_s_barrier();                   // CU-wide: t+1 visible
        READF(fA1, fB1, (t + 1) & 1);                   // independent of MFMA below
        MFMA32(fA0, fB0);
        ENDBAR();                                       // my reads drained before next DMA

        // ---- odd half: consume set1 (tile t+1), preload set0 (tile t+2) ----
        STAGE((t + 3 < 130) ? t + 3 : 129, (t + 1) & 1);
        asm volatile("s_waitcnt vmcnt(4)" ::: "memory");
        __builtin_amdgcn_s_barrier();
        if (t + 2 < 130) READF(fA0, fB0, t & 1);
        MFMA32(fA1, fB1);
        ENDBAR();
    }
    asm volatile("s_waitcnt vmcnt(0)" ::: "memory");   // drain ghost DMAs

    #undef STAGE
    #undef READF
    #undef MFMA32
    #undef ENDBAR

    // ---- epilogue: + bias, fp32 store ----
    #pragma unroll
    for (int m = 0; m < 8; ++m) {
        int orow = brow + wm * 128 + m * 16 + lk * 4;
        #pragma unroll
        for (int n = 0; n < 4; ++n) {
            int ocol = bcol + wn * 64 + n * 16 + lr;
            float bv = bias[ocol];
            #pragma unroll
            for (int j = 0; j < 4; ++j)
                out[(long)(orow + j) * DOUT + ocol] = acc[m][n][j] + bv;
        }
    }
}

extern "C" void kernel_launch(void* const* d_in, const int* in_sizes, int n_in,
                              void* d_out, int out_size, void* d_ws, size_t ws_size,
                              hipStream_t stream) {
    const float* x          = (const float*)d_in[0];
    const float* weight     = (const float*)d_in[1];
    const float* bias       = (const float*)d_in[2];
    const float* a_cache    = (const float*)d_in[3];
    const float* b_cache    = (const float*)d_in[4];
    const int*   b_start    = (const int*)d_in[5];
    const int*   b_adapter  = (const int*)d_in[6];
    const float* b_scaling  = (const float*)d_in[7];
    const int*   rpt        = (const int*)d_in[8];
    const int*   ranks      = (const int*)d_in[9];
    float* out = (float*)d_out;

    char* ws = (char*)d_ws;
    u16*   xb      = (u16*)ws;   ws += (size_t)T_TOK * DIN * 2;          // 64 MiB
    u16*   wb      = (u16*)ws;   ws += (size_t)DOUT * DIN * 2;           // 32 MiB
    u16*   ab      = (u16*)ws;   ws += (size_t)CACHE_LEN * DIN * 2;      // 4 MiB
    u16*   Bt      = (u16*)ws;   ws += (size_t)N_ADPT * DOUT * MAXR * 2; // 4 MiB
    u16*   xa      = (u16*)ws;   ws += (size_t)T_TOK * MAXR * 2;         // 1 MiB
    float* xa_part = (float*)ws; ws += (size_t)4 * T_TOK * MAXR * 4;     // 8 MiB

    cvt_all<<<2048, 256, 0, stream>>>(x, weight, a_cache, xb, wb, ab);
    build_bt<<<(N_ADPT * 8 * DOUT) / 256, 256, 0, stream>>>(b_cache, rpt, Bt);
    xa_kernel<<<(T_TOK / 128) * 4, 256, 0, stream>>>(xb, ab, b_start, b_adapter, rpt, xa_part);
    xa_fin<<<(T_TOK * MAXR + 255) / 256, 256, 0, stream>>>(xa_part, b_start, b_adapter, b_scaling, ranks, xa);
    gemm256_kernel<<<(T_TOK / 256) * (DOUT / 256), 512, 0, stream>>>(xb, wb, bias, xa, Bt, b_start, b_adapter, out);
}